// Round 5
// baseline (122.041 us; speedup 1.0000x reference)
//
#include <hip/hip_runtime.h>

// B=32, C=128, H=W=32, kern=2 -> pooled h=w=16
// out = B * sum_{i,c,h,w} [ log(mean_j dA(i,j)+eps) - log(mean_j dB(i,j)+eps) ]
//
// 2-param minimal form: shat = sqrt(log2e/2) * rsqrt(v); then
//   d_j = (1/k)*shat_j * exp2(-(shat_j*(z-mu_j))^2),  k = sqrt(log2e/2)
// per j: sub, mul, mul(neg-mod), exp2, fma  = 4 VALU + 1 trans, 8B LDS.
// 1/(32k) = 0.036794063 folds into the post-sum scale.
//
// Grid 4096 (= C*16h*2): 2 resident generations -> phase-1 memory of gen2
// overlaps phase-2 compute of gen1 (grid 2048 was a single generation, fully
// serial mem->compute). 8 pixels per block.
//
// LDS floats:
//   Q[side][p][64]: base = side*1092 + p*68; {mu_j, shat_j} at [2j, 2j+1]
//     p-stride 68 (16B-aligned, +4-bank shift/pixel); side offset 1092
//     (= +4 banks) so the two half-wave b128 broadcasts hit disjoint banks.
//   z: 2176 + b*17 + p   (17-stride: conflict-free column read)

#define GKL_EPS 1e-6f

__global__ __launch_bounds__(256) void gkl_main(
    const float* __restrict__ muA, const float* __restrict__ lvA,
    const float* __restrict__ muB, const float* __restrict__ lvB,
    const float* __restrict__ eps, double* __restrict__ ws)
{
    __shared__ float sh[2720];
    __shared__ float wsum[4];

    const int bid = blockIdx.x;          // 0..4095 = c(128) x h(16) x wh(2)
    const int c   = bid >> 5;
    const int h   = (bid >> 1) & 15;
    const int wh  = bid & 1;
    const int t   = threadIdx.x;
    const int b   = t >> 3;              // 0..31 = mixture index j
    const int wl  = t & 7;               // 0..7 local pixel
    const int w   = wh*8 + wl;

    // ---- Phase 1: pooled params, 1 (b,w) patch per thread, both sides ----
    {
        const int base = ((b*128 + c)*32 + 2*h)*32 + 2*w;

        float2 m0 = *(const float2*)(muA + base);
        float2 m1 = *(const float2*)(muA + base + 32);
        float2 l0 = *(const float2*)(lvA + base);
        float2 l1 = *(const float2*)(lvA + base + 32);
        float2 n0 = *(const float2*)(muB + base);
        float2 n1 = *(const float2*)(muB + base + 32);
        float2 k0 = *(const float2*)(lvB + base);
        float2 k1 = *(const float2*)(lvB + base + 32);
        float ev  = eps[((b*128 + c)*16 + h)*16 + w];

        float mu  = (m0.x + m0.y + m1.x + m1.y) * 0.25f;
        float var = (__expf(l0.x)+__expf(l0.y)+__expf(l1.x)+__expf(l1.y)) * 0.0625f;
        float rs  = __builtin_amdgcn_rsqf(var);
        *(float2*)(sh + wl*68 + 2*b) = make_float2(mu, 0.84932185f * rs);
        sh[2176 + b*17 + wl] = fmaf(var * rs, ev, mu);   // z = mu + sqrt(v)*eps

        float mub  = (n0.x + n0.y + n1.x + n1.y) * 0.25f;
        float varb = (__expf(k0.x)+__expf(k0.y)+__expf(k1.x)+__expf(k1.y)) * 0.0625f;
        float rsb  = __builtin_amdgcn_rsqf(varb);
        *(float2*)(sh + 1092 + wl*68 + 2*b) = make_float2(mub, 0.84932185f * rsb);
    }
    __syncthreads();

    // ---- Phase 2: wave = 32 samples x 2 sides, 2 pixels per wave ----
    const int lane = t & 63;
    const int wv   = t >> 6;             // 0..3
    const int i    = lane & 31;          // sample index
    const int side = lane >> 5;          // 0 = mixture A, 1 = mixture B
    const float* __restrict__ qp0 = sh + side*1092 + (wv*2)*68;
    const float* __restrict__ qp1 = qp0 + 68;
    const float z0 = sh[2176 + i*17 + wv*2];
    const float z1 = sh[2176 + i*17 + wv*2 + 1];

    float acc0 = 0.f, acc1 = 0.f;
    #pragma unroll
    for (int k = 0; k < 16; ++k) {       // j-pair per float4: {mu0,s0,mu1,s1}
        float4 f = *(const float4*)(qp0 + 4*k);
        float4 g = *(const float4*)(qp1 + 4*k);
        float d0 = z0 - f.x, e0 = d0 * f.y;
        acc0 = fmaf(f.y, exp2f(-(e0*e0)), acc0);
        float d1 = z0 - f.z, e1 = d1 * f.w;
        acc0 = fmaf(f.w, exp2f(-(e1*e1)), acc0);
        float d2 = z1 - g.x, e2 = d2 * g.y;
        acc1 = fmaf(g.y, exp2f(-(e2*e2)), acc1);
        float d3 = z1 - g.z, e3 = d3 * g.w;
        acc1 = fmaf(g.w, exp2f(-(e3*e3)), acc1);
    }
    float lg = __logf(fmaf(acc0, 0.036794063f, GKL_EPS))
             + __logf(fmaf(acc1, 0.036794063f, GKL_EPS));
    float tot = side ? -lg : lg;

    #pragma unroll
    for (int o = 32; o; o >>= 1) tot += __shfl_xor(tot, o, 64);
    if (lane == 0) wsum[wv] = tot;
    __syncthreads();
    if (t == 0)
        ws[bid] = (double)wsum[0] + (double)wsum[1] + (double)wsum[2] + (double)wsum[3];
}

__global__ __launch_bounds__(256) void gkl_final(
    const double* __restrict__ ws, float* __restrict__ out)
{
    __shared__ double part[4];
    const int t = threadIdx.x;
    double s = 0.0;
    for (int k = t; k < 4096; k += 256) s += ws[k];
    #pragma unroll
    for (int o = 32; o; o >>= 1) s += __shfl_xor(s, o, 64);
    if ((t & 63) == 0) part[t >> 6] = s;
    __syncthreads();
    if (t == 0) out[0] = (float)(32.0 * (part[0] + part[1] + part[2] + part[3]));
}

extern "C" void kernel_launch(void* const* d_in, const int* in_sizes, int n_in,
                              void* d_out, int out_size, void* d_ws, size_t ws_size,
                              hipStream_t stream) {
    const float* muA = (const float*)d_in[0];
    const float* lvA = (const float*)d_in[1];
    const float* muB = (const float*)d_in[2];
    const float* lvB = (const float*)d_in[3];
    const float* ep  = (const float*)d_in[4];
    double* ws = (double*)d_ws;          // 4096 doubles = 32 KB
    float* out = (float*)d_out;

    gkl_main<<<4096, 256, 0, stream>>>(muA, lvA, muB, lvB, ep, ws);
    gkl_final<<<1, 256, 0, stream>>>(ws, out);
}